// Round 1
// baseline (355.475 us; speedup 1.0000x reference)
//
#include <hip/hip_runtime.h>

#define D 1024
#define TPB 256   // 256 threads * float4 = 1024 floats = one row

// ---------------- Stage A: per-block partial column sums ----------------
__global__ void colsum_partial_kernel(const float* __restrict__ h0, const float* __restrict__ h1,
                                      const float* __restrict__ h2, const float* __restrict__ h3,
                                      int n0, int n1, int n2, int n3,
                                      float* __restrict__ partial)
{
    const int total = n0 + n1 + n2 + n3;
    const int t = threadIdx.x;
    float4 acc = make_float4(0.f, 0.f, 0.f, 0.f);
    for (int r = blockIdx.x; r < total; r += gridDim.x) {
        int lr = r; const float* p;
        if (lr < n0) p = h0;
        else { lr -= n0; if (lr < n1) p = h1;
               else { lr -= n1; if (lr < n2) p = h2;
                      else { lr -= n2; p = h3; } } }
        float4 v = reinterpret_cast<const float4*>(p + (size_t)lr * D)[t];
        acc.x += v.x; acc.y += v.y; acc.z += v.z; acc.w += v.w;
    }
    reinterpret_cast<float4*>(partial + (size_t)blockIdx.x * D)[t] = acc;
}

// ---------------- Stage B: reduce partials (deterministic) ----------------
__global__ void colsum_final_kernel(const float* __restrict__ partial,
                                    float* __restrict__ sums, int nb)
{
    const int c = blockIdx.x * blockDim.x + threadIdx.x;   // column 0..1023
    float s = 0.f;
    #pragma unroll 8
    for (int b = 0; b < nb; ++b) s += partial[(size_t)b * D + c];
    sums[c] = s;
}

// ---------------- GEMV: y = W @ (x*scale) + b  (one wave per row) --------
__global__ void gemv_kernel(const float* __restrict__ W, const float* __restrict__ x,
                            const float* __restrict__ bias, float scale,
                            float* __restrict__ y, float* __restrict__ y2)
{
    const int row  = blockIdx.x * 4 + (threadIdx.x >> 6);
    const int lane = threadIdx.x & 63;
    const float4* Wr = reinterpret_cast<const float4*>(W + (size_t)row * D);
    const float4* xv = reinterpret_cast<const float4*>(x);
    float s = 0.f;
    #pragma unroll
    for (int i = 0; i < 4; ++i) {
        float4 w  = Wr[i * 64 + lane];
        float4 xx = xv[i * 64 + lane];
        s += w.x * xx.x + w.y * xx.y + w.z * xx.z + w.w * xx.w;
    }
    #pragma unroll
    for (int off = 32; off; off >>= 1) s += __shfl_down(s, off, 64);
    if (lane == 0) {
        float r = s * scale + bias[row];
        y[row] = r;
        if (y2) y2[row] = r;
    }
}

// ---------------- Fused add + LayerNorm, one block per row ----------------
__global__ void ln_kernel(const float* __restrict__ h, const float* __restrict__ attn,
                          const float* __restrict__ gamma, const float* __restrict__ beta,
                          float* __restrict__ out)
{
    const int t = threadIdx.x;
    const size_t row = blockIdx.x;

    float4 x = reinterpret_cast<const float4*>(h + row * D)[t];
    float4 a = reinterpret_cast<const float4*>(attn)[t];
    x.x += a.x; x.y += a.y; x.z += a.z; x.w += a.w;

    float s  = x.x + x.y + x.z + x.w;
    float ss = x.x * x.x + x.y * x.y + x.z * x.z + x.w * x.w;
    #pragma unroll
    for (int off = 32; off; off >>= 1) {
        s  += __shfl_down(s,  off, 64);
        ss += __shfl_down(ss, off, 64);
    }

    __shared__ float red[8];
    const int wid = t >> 6, lane = t & 63;
    if (lane == 0) { red[wid] = s; red[4 + wid] = ss; }
    __syncthreads();
    if (t == 0) {
        float S  = red[0] + red[1] + red[2] + red[3];
        float SS = red[4] + red[5] + red[6] + red[7];
        float mu  = S * (1.f / D);
        float var = SS * (1.f / D) - mu * mu;
        red[0] = mu;
        red[1] = rsqrtf(var + 1e-5f);
    }
    __syncthreads();
    const float mu = red[0], rstd = red[1];

    float4 g  = reinterpret_cast<const float4*>(gamma)[t];
    float4 be = reinterpret_cast<const float4*>(beta)[t];
    float4 o;
    o.x = (x.x - mu) * rstd * g.x + be.x;
    o.y = (x.y - mu) * rstd * g.y + be.y;
    o.z = (x.z - mu) * rstd * g.z + be.z;
    o.w = (x.w - mu) * rstd * g.w + be.w;
    reinterpret_cast<float4*>(out)[row * (D / 4) + t] = o;
}

extern "C" void kernel_launch(void* const* d_in, const int* in_sizes, int n_in,
                              void* d_out, int out_size, void* d_ws, size_t ws_size,
                              hipStream_t stream)
{
    const float* h0    = (const float*)d_in[0];
    const float* h1    = (const float*)d_in[1];
    const float* h2    = (const float*)d_in[2];
    const float* h3    = (const float*)d_in[3];
    const float* Wp    = (const float*)d_in[4];
    const float* bp    = (const float*)d_in[5];
    const float* Wv    = (const float*)d_in[6];
    const float* bv    = (const float*)d_in[7];
    const float* Wo    = (const float*)d_in[8];
    const float* bo    = (const float*)d_in[9];
    const float* gamma = (const float*)d_in[10];
    const float* beta  = (const float*)d_in[11];

    const int n0 = in_sizes[0] / D;
    const int n1 = in_sizes[1] / D;
    const int n2 = in_sizes[2] / D;
    const int n3 = in_sizes[3] / D;
    const int total = n0 + n1 + n2 + n3;

    float* ws      = (float*)d_ws;
    float* sums    = ws;          // 1024
    float* gvec    = ws + 1024;   // 1024
    float* vvec    = ws + 2048;   // 1024
    float* attn    = ws + 3072;   // 1024
    float* partial = ws + 4096;   // NB * 1024

    // choose partial-block count that fits in ws (deterministic per ws_size)
    long nbmax = ((long)(ws_size / sizeof(float)) - 4096) / D;
    int NB = 1024;
    if (nbmax < NB) NB = (int)nbmax;
    if (NB < 1) NB = 1;
    if (NB > total) NB = total;

    float* out = (float*)d_out;

    colsum_partial_kernel<<<NB, TPB, 0, stream>>>(h0, h1, h2, h3, n0, n1, n2, n3, partial);
    colsum_final_kernel<<<4, 256, 0, stream>>>(partial, sums, NB);

    // global_vec = Wp @ mean + bp   (also written to d_out[0:1024])
    gemv_kernel<<<256, 256, 0, stream>>>(Wp, sums, bp, 1.0f / (float)total, gvec, out);
    // v = Wv @ global_vec + bv
    gemv_kernel<<<256, 256, 0, stream>>>(Wv, gvec, bv, 1.0f, vvec, nullptr);
    // attn_out = Wo @ v + bo
    gemv_kernel<<<256, 256, 0, stream>>>(Wo, vvec, bo, 1.0f, attn, nullptr);

    size_t off = 1024;
    ln_kernel<<<n0, TPB, 0, stream>>>(h0, attn, gamma, beta, out + off); off += (size_t)n0 * D;
    ln_kernel<<<n1, TPB, 0, stream>>>(h1, attn, gamma, beta, out + off); off += (size_t)n1 * D;
    ln_kernel<<<n2, TPB, 0, stream>>>(h2, attn, gamma, beta, out + off); off += (size_t)n2 * D;
    ln_kernel<<<n3, TPB, 0, stream>>>(h3, attn, gamma, beta, out + off);
}

// Round 3
// 256.613 us; speedup vs baseline: 1.3853x; 1.3853x over previous
//
#include <hip/hip_runtime.h>

#define D 1024
#define TPB 256

typedef float floatx4 __attribute__((ext_vector_type(4)));

// ---------------- Stage A: per-block partial column sums ----------------
__global__ void colsum_partial_kernel(const float* __restrict__ h0, const float* __restrict__ h1,
                                      const float* __restrict__ h2, const float* __restrict__ h3,
                                      int n0, int n1, int n2, int n3,
                                      float* __restrict__ partial)
{
    const int total = n0 + n1 + n2 + n3;
    const int t = threadIdx.x;
    float4 acc = make_float4(0.f, 0.f, 0.f, 0.f);
    #pragma unroll 4
    for (int r = blockIdx.x; r < total; r += gridDim.x) {
        int lr = r; const float* p;
        if (lr < n0) p = h0;
        else { lr -= n0; if (lr < n1) p = h1;
               else { lr -= n1; if (lr < n2) p = h2;
                      else { lr -= n2; p = h3; } } }
        float4 v = reinterpret_cast<const float4*>(p + (size_t)lr * D)[t];
        acc.x += v.x; acc.y += v.y; acc.z += v.z; acc.w += v.w;
    }
    reinterpret_cast<float4*>(partial + (size_t)blockIdx.x * D)[t] = acc;
}

// ------------- Stage B: reduce partials, 64 blocks x 16 cols each -------
__global__ void colsum_final_kernel(const float* __restrict__ partial,
                                    float* __restrict__ sums, int nb)
{
    const int t = threadIdx.x;
    const int colg = blockIdx.x * 16;          // 64 blocks * 16 cols = 1024
    const int c = colg + (t & 15);
    const int slice = t >> 4;                  // 0..15
    float s = 0.f;
    for (int b = slice; b < nb; b += 16)
        s += partial[(size_t)b * D + c];
    __shared__ float red[256];
    red[t] = s;
    __syncthreads();
    if (t < 16) {
        float tot = 0.f;
        #pragma unroll
        for (int k = 0; k < 16; ++k) tot += red[t + 16 * k];
        sums[colg + t] = tot;
    }
}

// ---------------- GEMV: y = W @ (x*scale) + b  (one wave per row) --------
__global__ void gemv_kernel(const float* __restrict__ W, const float* __restrict__ x,
                            const float* __restrict__ bias, float scale,
                            float* __restrict__ y, float* __restrict__ y2)
{
    const int row  = blockIdx.x * 4 + (threadIdx.x >> 6);
    const int lane = threadIdx.x & 63;
    const float4* Wr = reinterpret_cast<const float4*>(W + (size_t)row * D);
    const float4* xv = reinterpret_cast<const float4*>(x);
    float s = 0.f;
    #pragma unroll
    for (int i = 0; i < 4; ++i) {
        float4 w  = Wr[i * 64 + lane];
        float4 xx = xv[i * 64 + lane];
        s += w.x * xx.x + w.y * xx.y + w.z * xx.z + w.w * xx.w;
    }
    #pragma unroll
    for (int off = 32; off; off >>= 1) s += __shfl_down(s, off, 64);
    if (lane == 0) {
        float r = s * scale + bias[row];
        y[row] = r;
        if (y2) y2[row] = r;
    }
}

// -------- Fused add + LayerNorm: one WAVE per row, no barriers -----------
// Processes all 4 tensors; iterates rows in REVERSE global order so the
// tail of h (left resident in L3 by pass 1) is consumed while still hot.
__global__ void ln_fused_kernel(const float* __restrict__ h0, const float* __restrict__ h1,
                                const float* __restrict__ h2, const float* __restrict__ h3,
                                int n0, int n1, int n2, int n3,
                                const float* __restrict__ attn,
                                const float* __restrict__ gamma,
                                const float* __restrict__ beta,
                                float* __restrict__ out /* already offset by D */)
{
    const int total = n0 + n1 + n2 + n3;
    const int lane  = threadIdx.x & 63;
    const int gw    = (blockIdx.x * blockDim.x + threadIdx.x) >> 6;  // global wave id
    const int nw    = (gridDim.x * blockDim.x) >> 6;

    // hoist broadcast vectors into registers (16 floats each per lane)
    float4 a[4], g[4], b[4];
    #pragma unroll
    for (int i = 0; i < 4; ++i) {
        a[i] = reinterpret_cast<const float4*>(attn)[i * 64 + lane];
        g[i] = reinterpret_cast<const float4*>(gamma)[i * 64 + lane];
        b[i] = reinterpret_cast<const float4*>(beta)[i * 64 + lane];
    }

    for (int r = gw; r < total; r += nw) {
        const int row = total - 1 - r;          // reverse order for L3 reuse
        int lr = row; const float* p;
        if (lr < n0) p = h0;
        else { lr -= n0; if (lr < n1) p = h1;
               else { lr -= n1; if (lr < n2) p = h2;
                      else { lr -= n2; p = h3; } } }
        const float4* hp = reinterpret_cast<const float4*>(p + (size_t)lr * D);

        float4 x[4];
        #pragma unroll
        for (int i = 0; i < 4; ++i) x[i] = hp[i * 64 + lane];

        float s = 0.f, ss = 0.f;
        #pragma unroll
        for (int i = 0; i < 4; ++i) {
            x[i].x += a[i].x; x[i].y += a[i].y; x[i].z += a[i].z; x[i].w += a[i].w;
            s  += x[i].x + x[i].y + x[i].z + x[i].w;
            ss += x[i].x * x[i].x + x[i].y * x[i].y + x[i].z * x[i].z + x[i].w * x[i].w;
        }
        #pragma unroll
        for (int m = 32; m; m >>= 1) {
            s  += __shfl_xor(s,  m, 64);
            ss += __shfl_xor(ss, m, 64);
        }
        const float mu   = s * (1.f / D);
        const float rstd = rsqrtf(ss * (1.f / D) - mu * mu + 1e-5f);

        floatx4* op = reinterpret_cast<floatx4*>(out + (size_t)row * D);
        #pragma unroll
        for (int i = 0; i < 4; ++i) {
            floatx4 o;
            o.x = (x[i].x - mu) * rstd * g[i].x + b[i].x;
            o.y = (x[i].y - mu) * rstd * g[i].y + b[i].y;
            o.z = (x[i].z - mu) * rstd * g[i].z + b[i].z;
            o.w = (x[i].w - mu) * rstd * g[i].w + b[i].w;
            __builtin_nontemporal_store(o, &op[i * 64 + lane]);
        }
    }
}

extern "C" void kernel_launch(void* const* d_in, const int* in_sizes, int n_in,
                              void* d_out, int out_size, void* d_ws, size_t ws_size,
                              hipStream_t stream)
{
    const float* h0    = (const float*)d_in[0];
    const float* h1    = (const float*)d_in[1];
    const float* h2    = (const float*)d_in[2];
    const float* h3    = (const float*)d_in[3];
    const float* Wp    = (const float*)d_in[4];
    const float* bp    = (const float*)d_in[5];
    const float* Wv    = (const float*)d_in[6];
    const float* bv    = (const float*)d_in[7];
    const float* Wo    = (const float*)d_in[8];
    const float* bo    = (const float*)d_in[9];
    const float* gamma = (const float*)d_in[10];
    const float* beta  = (const float*)d_in[11];

    const int n0 = in_sizes[0] / D;
    const int n1 = in_sizes[1] / D;
    const int n2 = in_sizes[2] / D;
    const int n3 = in_sizes[3] / D;
    const int total = n0 + n1 + n2 + n3;

    float* ws      = (float*)d_ws;
    float* sums    = ws;          // 1024
    float* gvec    = ws + 1024;   // 1024
    float* vvec    = ws + 2048;   // 1024
    float* attn    = ws + 3072;   // 1024
    float* partial = ws + 4096;   // NB * 1024

    long nbmax = ((long)(ws_size / sizeof(float)) - 4096) / D;
    int NB = 2048;
    if (nbmax < NB) NB = (int)nbmax;
    if (NB < 1) NB = 1;
    if (NB > total) NB = total;

    float* out = (float*)d_out;

    colsum_partial_kernel<<<NB, TPB, 0, stream>>>(h0, h1, h2, h3, n0, n1, n2, n3, partial);
    colsum_final_kernel<<<64, 256, 0, stream>>>(partial, sums, NB);

    gemv_kernel<<<256, 256, 0, stream>>>(Wp, sums, bp, 1.0f / (float)total, gvec, out);
    gemv_kernel<<<256, 256, 0, stream>>>(Wv, gvec, bv, 1.0f, vvec, nullptr);
    gemv_kernel<<<256, 256, 0, stream>>>(Wo, vvec, bo, 1.0f, attn, nullptr);

    ln_fused_kernel<<<2048, TPB, 0, stream>>>(h0, h1, h2, h3, n0, n1, n2, n3,
                                              attn, gamma, beta, out + D);
}

// Round 4
// 248.105 us; speedup vs baseline: 1.4328x; 1.0343x over previous
//
#include <hip/hip_runtime.h>

#define D 1024
#define TPB 256

typedef float floatx4 __attribute__((ext_vector_type(4)));

// ---------------- Stage A: per-block partial column sums ----------------
// Rows < split are loaded nontemporally (no L3 pollution); rows >= split
// load normally so the ~200MB tail stays resident in Infinity Cache for
// pass 2 (which consumes rows in reverse order).
__global__ void colsum_partial_kernel(const float* __restrict__ h0, const float* __restrict__ h1,
                                      const float* __restrict__ h2, const float* __restrict__ h3,
                                      int n0, int n1, int n2, int n3, int split,
                                      float* __restrict__ partial)
{
    const int total = n0 + n1 + n2 + n3;
    const int t = threadIdx.x;
    floatx4 acc = (floatx4)(0.f);
    for (int r = blockIdx.x; r < total; r += gridDim.x) {
        int lr = r; const float* p;
        if (lr < n0) p = h0;
        else { lr -= n0; if (lr < n1) p = h1;
               else { lr -= n1; if (lr < n2) p = h2;
                      else { lr -= n2; p = h3; } } }
        const floatx4* hp = reinterpret_cast<const floatx4*>(p + (size_t)lr * D);
        floatx4 v;
        if (r < split) v = __builtin_nontemporal_load(hp + t);
        else           v = hp[t];
        acc += v;
    }
    reinterpret_cast<floatx4*>(partial + (size_t)blockIdx.x * D)[t] = acc;
}

// ------------- Stage B: reduce partials, 64 blocks x 16 cols each -------
__global__ void colsum_final_kernel(const float* __restrict__ partial,
                                    float* __restrict__ sums, int nb)
{
    const int t = threadIdx.x;
    const int colg = blockIdx.x * 16;          // 64 blocks * 16 cols = 1024
    const int c = colg + (t & 15);
    const int slice = t >> 4;                  // 0..15
    float s = 0.f;
    for (int b = slice; b < nb; b += 16)
        s += partial[(size_t)b * D + c];
    __shared__ float red[256];
    red[t] = s;
    __syncthreads();
    if (t < 16) {
        float tot = 0.f;
        #pragma unroll
        for (int k = 0; k < 16; ++k) tot += red[t + 16 * k];
        sums[colg + t] = tot;
    }
}

// ---------------- GEMV: y = W @ (x*scale) + b  (one wave per row) --------
__global__ void gemv_kernel(const float* __restrict__ W, const float* __restrict__ x,
                            const float* __restrict__ bias, float scale,
                            float* __restrict__ y, float* __restrict__ y2)
{
    const int row  = blockIdx.x * 4 + (threadIdx.x >> 6);
    const int lane = threadIdx.x & 63;
    const float4* Wr = reinterpret_cast<const float4*>(W + (size_t)row * D);
    const float4* xv = reinterpret_cast<const float4*>(x);
    float s = 0.f;
    #pragma unroll
    for (int i = 0; i < 4; ++i) {
        float4 w  = Wr[i * 64 + lane];
        float4 xx = xv[i * 64 + lane];
        s += w.x * xx.x + w.y * xx.y + w.z * xx.z + w.w * xx.w;
    }
    #pragma unroll
    for (int off = 32; off; off >>= 1) s += __shfl_down(s, off, 64);
    if (lane == 0) {
        float r = s * scale + bias[row];
        y[row] = r;
        if (y2) y2[row] = r;
    }
}

// -------- Fused add + LayerNorm: one WAVE per row, no barriers -----------
// Reverse global order: tail rows (>= split, L3-resident from pass 1) are
// consumed first via cached loads; cold front rows use NT loads. NT stores
// keep the 410MB output stream from evicting the h tail.
__global__ void ln_fused_kernel(const float* __restrict__ h0, const float* __restrict__ h1,
                                const float* __restrict__ h2, const float* __restrict__ h3,
                                int n0, int n1, int n2, int n3, int split,
                                const float* __restrict__ attn,
                                const float* __restrict__ gamma,
                                const float* __restrict__ beta,
                                float* __restrict__ out /* already offset by D */)
{
    const int total = n0 + n1 + n2 + n3;
    const int lane  = threadIdx.x & 63;
    const int gw    = (blockIdx.x * blockDim.x + threadIdx.x) >> 6;  // global wave id
    const int nw    = (gridDim.x * blockDim.x) >> 6;

    // hoist broadcast vectors into registers (16 floats each per lane)
    floatx4 a[4], g[4], b[4];
    #pragma unroll
    for (int i = 0; i < 4; ++i) {
        a[i] = reinterpret_cast<const floatx4*>(attn)[i * 64 + lane];
        g[i] = reinterpret_cast<const floatx4*>(gamma)[i * 64 + lane];
        b[i] = reinterpret_cast<const floatx4*>(beta)[i * 64 + lane];
    }

    for (int r = gw; r < total; r += nw) {
        const int row = total - 1 - r;          // reverse order for L3 reuse
        int lr = row; const float* p;
        if (lr < n0) p = h0;
        else { lr -= n0; if (lr < n1) p = h1;
               else { lr -= n1; if (lr < n2) p = h2;
                      else { lr -= n2; p = h3; } } }
        const floatx4* hp = reinterpret_cast<const floatx4*>(p + (size_t)lr * D);

        floatx4 x[4];
        if (row < split) {
            #pragma unroll
            for (int i = 0; i < 4; ++i) x[i] = __builtin_nontemporal_load(hp + i * 64 + lane);
        } else {
            #pragma unroll
            for (int i = 0; i < 4; ++i) x[i] = hp[i * 64 + lane];
        }

        float s = 0.f, ss = 0.f;
        #pragma unroll
        for (int i = 0; i < 4; ++i) {
            x[i] += a[i];
            s  += x[i].x + x[i].y + x[i].z + x[i].w;
            ss += x[i].x * x[i].x + x[i].y * x[i].y + x[i].z * x[i].z + x[i].w * x[i].w;
        }
        #pragma unroll
        for (int m = 32; m; m >>= 1) {
            s  += __shfl_xor(s,  m, 64);
            ss += __shfl_xor(ss, m, 64);
        }
        const float mu   = s * (1.f / D);
        const float rstd = rsqrtf(ss * (1.f / D) - mu * mu + 1e-5f);

        floatx4* op = reinterpret_cast<floatx4*>(out + (size_t)row * D);
        #pragma unroll
        for (int i = 0; i < 4; ++i) {
            floatx4 o;
            o.x = (x[i].x - mu) * rstd * g[i].x + b[i].x;
            o.y = (x[i].y - mu) * rstd * g[i].y + b[i].y;
            o.z = (x[i].z - mu) * rstd * g[i].z + b[i].z;
            o.w = (x[i].w - mu) * rstd * g[i].w + b[i].w;
            __builtin_nontemporal_store(o, op + i * 64 + lane);
        }
    }
}

extern "C" void kernel_launch(void* const* d_in, const int* in_sizes, int n_in,
                              void* d_out, int out_size, void* d_ws, size_t ws_size,
                              hipStream_t stream)
{
    const float* h0    = (const float*)d_in[0];
    const float* h1    = (const float*)d_in[1];
    const float* h2    = (const float*)d_in[2];
    const float* h3    = (const float*)d_in[3];
    const float* Wp    = (const float*)d_in[4];
    const float* bp    = (const float*)d_in[5];
    const float* Wv    = (const float*)d_in[6];
    const float* bv    = (const float*)d_in[7];
    const float* Wo    = (const float*)d_in[8];
    const float* bo    = (const float*)d_in[9];
    const float* gamma = (const float*)d_in[10];
    const float* beta  = (const float*)d_in[11];

    const int n0 = in_sizes[0] / D;
    const int n1 = in_sizes[1] / D;
    const int n2 = in_sizes[2] / D;
    const int n3 = in_sizes[3] / D;
    const int total = n0 + n1 + n2 + n3;

    // keep the last ~200MB of rows L3-resident for pass 2
    int tail_rows = (200 << 20) / (D * 4);   // 51200 rows
    int split = total - tail_rows;
    if (split < 0) split = 0;

    float* ws      = (float*)d_ws;
    float* sums    = ws;          // 1024
    float* gvec    = ws + 1024;   // 1024
    float* vvec    = ws + 2048;   // 1024
    float* attn    = ws + 3072;   // 1024
    float* partial = ws + 4096;   // NB * 1024

    long nbmax = ((long)(ws_size / sizeof(float)) - 4096) / D;
    int NB = 2048;
    if (nbmax < NB) NB = (int)nbmax;
    if (NB < 1) NB = 1;
    if (NB > total) NB = total;

    float* out = (float*)d_out;

    colsum_partial_kernel<<<NB, TPB, 0, stream>>>(h0, h1, h2, h3, n0, n1, n2, n3, split, partial);
    colsum_final_kernel<<<64, 256, 0, stream>>>(partial, sums, NB);

    gemv_kernel<<<256, 256, 0, stream>>>(Wp, sums, bp, 1.0f / (float)total, gvec, out);
    gemv_kernel<<<256, 256, 0, stream>>>(Wv, gvec, bv, 1.0f, vvec, nullptr);
    gemv_kernel<<<256, 256, 0, stream>>>(Wo, vvec, bo, 1.0f, attn, nullptr);

    ln_fused_kernel<<<2048, TPB, 0, stream>>>(h0, h1, h2, h3, n0, n1, n2, n3, split,
                                              attn, gamma, beta, out + D);
}

// Round 5
// 228.220 us; speedup vs baseline: 1.5576x; 1.0871x over previous
//
#include <hip/hip_runtime.h>

#define D 1024
#define TPB 256

typedef float floatx4 __attribute__((ext_vector_type(4)));

__device__ __forceinline__ const float* rowptr(int row,
    const float* __restrict__ h0, const float* __restrict__ h1,
    const float* __restrict__ h2, const float* __restrict__ h3,
    int n0, int n1, int n2, int n3)
{
    if (row < n0) return h0 + (size_t)row * D;
    row -= n0; if (row < n1) return h1 + (size_t)row * D;
    row -= n1; if (row < n2) return h2 + (size_t)row * D;
    row -= n2; return h3 + (size_t)row * D;
}

// ---------------- Stage A: per-block partial column sums ----------------
// Front rows (< split): nontemporal loads (no L3 alloc). Tail rows: cached
// so they stay L3-resident for pass 2. 4 rows in flight per wave.
__global__ void colsum_partial_kernel(const float* __restrict__ h0, const float* __restrict__ h1,
                                      const float* __restrict__ h2, const float* __restrict__ h3,
                                      int n0, int n1, int n2, int n3, int split,
                                      float* __restrict__ partial)
{
    const int total = n0 + n1 + n2 + n3;
    const int t = threadIdx.x;
    const int g = gridDim.x;
    floatx4 acc0 = (floatx4)(0.f), acc1 = (floatx4)(0.f),
            acc2 = (floatx4)(0.f), acc3 = (floatx4)(0.f);

    int r = blockIdx.x;
    // NT front, 4-wide
    for (; r + 3 * g < split; r += 4 * g) {
        const floatx4* p0 = reinterpret_cast<const floatx4*>(rowptr(r,         h0,h1,h2,h3,n0,n1,n2,n3));
        const floatx4* p1 = reinterpret_cast<const floatx4*>(rowptr(r + g,     h0,h1,h2,h3,n0,n1,n2,n3));
        const floatx4* p2 = reinterpret_cast<const floatx4*>(rowptr(r + 2 * g, h0,h1,h2,h3,n0,n1,n2,n3));
        const floatx4* p3 = reinterpret_cast<const floatx4*>(rowptr(r + 3 * g, h0,h1,h2,h3,n0,n1,n2,n3));
        acc0 += __builtin_nontemporal_load(p0 + t);
        acc1 += __builtin_nontemporal_load(p1 + t);
        acc2 += __builtin_nontemporal_load(p2 + t);
        acc3 += __builtin_nontemporal_load(p3 + t);
    }
    for (; r < split; r += g) {
        const floatx4* p0 = reinterpret_cast<const floatx4*>(rowptr(r, h0,h1,h2,h3,n0,n1,n2,n3));
        acc0 += __builtin_nontemporal_load(p0 + t);
    }
    // cached tail, 4-wide
    for (; r + 3 * g < total; r += 4 * g) {
        const floatx4* p0 = reinterpret_cast<const floatx4*>(rowptr(r,         h0,h1,h2,h3,n0,n1,n2,n3));
        const floatx4* p1 = reinterpret_cast<const floatx4*>(rowptr(r + g,     h0,h1,h2,h3,n0,n1,n2,n3));
        const floatx4* p2 = reinterpret_cast<const floatx4*>(rowptr(r + 2 * g, h0,h1,h2,h3,n0,n1,n2,n3));
        const floatx4* p3 = reinterpret_cast<const floatx4*>(rowptr(r + 3 * g, h0,h1,h2,h3,n0,n1,n2,n3));
        acc0 += p0[t]; acc1 += p1[t]; acc2 += p2[t]; acc3 += p3[t];
    }
    for (; r < total; r += g) {
        const floatx4* p0 = reinterpret_cast<const floatx4*>(rowptr(r, h0,h1,h2,h3,n0,n1,n2,n3));
        acc0 += p0[t];
    }
    acc0 += acc1; acc2 += acc3; acc0 += acc2;
    reinterpret_cast<floatx4*>(partial + (size_t)blockIdx.x * D)[t] = acc0;
}

// ------------- Stage B: reduce partials, 128 blocks x 8 cols each -------
__global__ void colsum_final_kernel(const float* __restrict__ partial,
                                    float* __restrict__ sums, int nb)
{
    const int t = threadIdx.x;
    const int colg = blockIdx.x * 8;           // 128 blocks * 8 cols = 1024
    const int c = colg + (t & 7);
    const int slice = t >> 3;                  // 0..31
    float s = 0.f;
    for (int b = slice; b < nb; b += 32)
        s += partial[(size_t)b * D + c];
    __shared__ float red[256];
    red[t] = s;
    __syncthreads();
    if (t < 8) {
        float tot = 0.f;
        #pragma unroll
        for (int k = 0; k < 32; ++k) tot += red[t + 8 * k];
        sums[colg + t] = tot;
    }
}

// ---------------- GEMV: y = W @ (x*scale) + b  (one wave per row) --------
__global__ void gemv_kernel(const float* __restrict__ W, const float* __restrict__ x,
                            const float* __restrict__ bias, float scale,
                            float* __restrict__ y, float* __restrict__ y2)
{
    const int row  = blockIdx.x * 4 + (threadIdx.x >> 6);
    const int lane = threadIdx.x & 63;
    const float4* Wr = reinterpret_cast<const float4*>(W + (size_t)row * D);
    const float4* xv = reinterpret_cast<const float4*>(x);
    float s = 0.f;
    #pragma unroll
    for (int i = 0; i < 4; ++i) {
        float4 w  = Wr[i * 64 + lane];
        float4 xx = xv[i * 64 + lane];
        s += w.x * xx.x + w.y * xx.y + w.z * xx.z + w.w * xx.w;
    }
    #pragma unroll
    for (int off = 32; off; off >>= 1) s += __shfl_down(s, off, 64);
    if (lane == 0) {
        float r = s * scale + bias[row];
        y[row] = r;
        if (y2) y2[row] = r;
    }
}

// -------- Fused add + LayerNorm: one WAVE per row, 2 rows in flight ------
// Reverse sweep: L3-resident tail first (cached loads), cold front NT.
__global__ void ln_fused_kernel(const float* __restrict__ h0, const float* __restrict__ h1,
                                const float* __restrict__ h2, const float* __restrict__ h3,
                                int n0, int n1, int n2, int n3, int split,
                                const float* __restrict__ attn,
                                const float* __restrict__ gamma,
                                const float* __restrict__ beta,
                                float* __restrict__ out /* already offset by D */)
{
    const int total = n0 + n1 + n2 + n3;
    const int lane  = threadIdx.x & 63;
    const int gw    = (blockIdx.x * blockDim.x + threadIdx.x) >> 6;
    const int nw    = (gridDim.x * blockDim.x) >> 6;

    floatx4 a[4], g[4], b[4];
    #pragma unroll
    for (int i = 0; i < 4; ++i) {
        a[i] = reinterpret_cast<const floatx4*>(attn)[i * 64 + lane];
        g[i] = reinterpret_cast<const floatx4*>(gamma)[i * 64 + lane];
        b[i] = reinterpret_cast<const floatx4*>(beta)[i * 64 + lane];
    }

    int r = gw;
    for (; r + nw < total; r += 2 * nw) {
        const int row0 = total - 1 - r;
        const int row1 = total - 1 - r - nw;
        const floatx4* hp0 = reinterpret_cast<const floatx4*>(rowptr(row0, h0,h1,h2,h3,n0,n1,n2,n3));
        const floatx4* hp1 = reinterpret_cast<const floatx4*>(rowptr(row1, h0,h1,h2,h3,n0,n1,n2,n3));

        floatx4 x0[4], x1[4];
        if (row0 < split) {
            #pragma unroll
            for (int i = 0; i < 4; ++i) x0[i] = __builtin_nontemporal_load(hp0 + i * 64 + lane);
        } else {
            #pragma unroll
            for (int i = 0; i < 4; ++i) x0[i] = hp0[i * 64 + lane];
        }
        if (row1 < split) {
            #pragma unroll
            for (int i = 0; i < 4; ++i) x1[i] = __builtin_nontemporal_load(hp1 + i * 64 + lane);
        } else {
            #pragma unroll
            for (int i = 0; i < 4; ++i) x1[i] = hp1[i * 64 + lane];
        }

        float s0 = 0.f, ss0 = 0.f, s1 = 0.f, ss1 = 0.f;
        #pragma unroll
        for (int i = 0; i < 4; ++i) {
            x0[i] += a[i];
            x1[i] += a[i];
            s0  += x0[i].x + x0[i].y + x0[i].z + x0[i].w;
            ss0 += x0[i].x * x0[i].x + x0[i].y * x0[i].y + x0[i].z * x0[i].z + x0[i].w * x0[i].w;
            s1  += x1[i].x + x1[i].y + x1[i].z + x1[i].w;
            ss1 += x1[i].x * x1[i].x + x1[i].y * x1[i].y + x1[i].z * x1[i].z + x1[i].w * x1[i].w;
        }
        #pragma unroll
        for (int m = 32; m; m >>= 1) {
            s0  += __shfl_xor(s0,  m, 64);
            ss0 += __shfl_xor(ss0, m, 64);
            s1  += __shfl_xor(s1,  m, 64);
            ss1 += __shfl_xor(ss1, m, 64);
        }
        const float mu0   = s0 * (1.f / D);
        const float rstd0 = rsqrtf(ss0 * (1.f / D) - mu0 * mu0 + 1e-5f);
        const float mu1   = s1 * (1.f / D);
        const float rstd1 = rsqrtf(ss1 * (1.f / D) - mu1 * mu1 + 1e-5f);

        floatx4* op0 = reinterpret_cast<floatx4*>(out + (size_t)row0 * D);
        floatx4* op1 = reinterpret_cast<floatx4*>(out + (size_t)row1 * D);
        #pragma unroll
        for (int i = 0; i < 4; ++i) {
            floatx4 o0, o1;
            o0.x = (x0[i].x - mu0) * rstd0 * g[i].x + b[i].x;
            o0.y = (x0[i].y - mu0) * rstd0 * g[i].y + b[i].y;
            o0.z = (x0[i].z - mu0) * rstd0 * g[i].z + b[i].z;
            o0.w = (x0[i].w - mu0) * rstd0 * g[i].w + b[i].w;
            o1.x = (x1[i].x - mu1) * rstd1 * g[i].x + b[i].x;
            o1.y = (x1[i].y - mu1) * rstd1 * g[i].y + b[i].y;
            o1.z = (x1[i].z - mu1) * rstd1 * g[i].z + b[i].z;
            o1.w = (x1[i].w - mu1) * rstd1 * g[i].w + b[i].w;
            __builtin_nontemporal_store(o0, op0 + i * 64 + lane);
            __builtin_nontemporal_store(o1, op1 + i * 64 + lane);
        }
    }
    if (r < total) {
        const int row = total - 1 - r;
        const floatx4* hp = reinterpret_cast<const floatx4*>(rowptr(row, h0,h1,h2,h3,n0,n1,n2,n3));
        floatx4 x[4];
        if (row < split) {
            #pragma unroll
            for (int i = 0; i < 4; ++i) x[i] = __builtin_nontemporal_load(hp + i * 64 + lane);
        } else {
            #pragma unroll
            for (int i = 0; i < 4; ++i) x[i] = hp[i * 64 + lane];
        }
        float s = 0.f, ss = 0.f;
        #pragma unroll
        for (int i = 0; i < 4; ++i) {
            x[i] += a[i];
            s  += x[i].x + x[i].y + x[i].z + x[i].w;
            ss += x[i].x * x[i].x + x[i].y * x[i].y + x[i].z * x[i].z + x[i].w * x[i].w;
        }
        #pragma unroll
        for (int m = 32; m; m >>= 1) {
            s  += __shfl_xor(s,  m, 64);
            ss += __shfl_xor(ss, m, 64);
        }
        const float mu   = s * (1.f / D);
        const float rstd = rsqrtf(ss * (1.f / D) - mu * mu + 1e-5f);
        floatx4* op = reinterpret_cast<floatx4*>(out + (size_t)row * D);
        #pragma unroll
        for (int i = 0; i < 4; ++i) {
            floatx4 o;
            o.x = (x[i].x - mu) * rstd * g[i].x + b[i].x;
            o.y = (x[i].y - mu) * rstd * g[i].y + b[i].y;
            o.z = (x[i].z - mu) * rstd * g[i].z + b[i].z;
            o.w = (x[i].w - mu) * rstd * g[i].w + b[i].w;
            __builtin_nontemporal_store(o, op + i * 64 + lane);
        }
    }
}

extern "C" void kernel_launch(void* const* d_in, const int* in_sizes, int n_in,
                              void* d_out, int out_size, void* d_ws, size_t ws_size,
                              hipStream_t stream)
{
    const float* h0    = (const float*)d_in[0];
    const float* h1    = (const float*)d_in[1];
    const float* h2    = (const float*)d_in[2];
    const float* h3    = (const float*)d_in[3];
    const float* Wp    = (const float*)d_in[4];
    const float* bp    = (const float*)d_in[5];
    const float* Wv    = (const float*)d_in[6];
    const float* bv    = (const float*)d_in[7];
    const float* Wo    = (const float*)d_in[8];
    const float* bo    = (const float*)d_in[9];
    const float* gamma = (const float*)d_in[10];
    const float* beta  = (const float*)d_in[11];

    const int n0 = in_sizes[0] / D;
    const int n1 = in_sizes[1] / D;
    const int n2 = in_sizes[2] / D;
    const int n3 = in_sizes[3] / D;
    const int total = n0 + n1 + n2 + n3;

    // keep the last ~200MB of rows L3-resident for pass 2
    int tail_rows = (200 << 20) / (D * 4);   // 51200 rows
    int split = total - tail_rows;
    if (split < 0) split = 0;

    float* ws      = (float*)d_ws;
    float* sums    = ws;          // 1024
    float* gvec    = ws + 1024;   // 1024
    float* vvec    = ws + 2048;   // 1024
    float* attn    = ws + 3072;   // 1024
    float* partial = ws + 4096;   // NB * 1024

    long nbmax = ((long)(ws_size / sizeof(float)) - 4096) / D;
    int NB = 2048;
    if (nbmax < NB) NB = (int)nbmax;
    if (NB < 1) NB = 1;
    if (NB > total) NB = total;

    float* out = (float*)d_out;

    colsum_partial_kernel<<<NB, TPB, 0, stream>>>(h0, h1, h2, h3, n0, n1, n2, n3, split, partial);
    colsum_final_kernel<<<128, 256, 0, stream>>>(partial, sums, NB);

    gemv_kernel<<<256, 256, 0, stream>>>(Wp, sums, bp, 1.0f / (float)total, gvec, out);
    gemv_kernel<<<256, 256, 0, stream>>>(Wv, gvec, bv, 1.0f, vvec, nullptr);
    gemv_kernel<<<256, 256, 0, stream>>>(Wo, vvec, bo, 1.0f, attn, nullptr);

    ln_fused_kernel<<<2048, TPB, 0, stream>>>(h0, h1, h2, h3, n0, n1, n2, n3, split,
                                              attn, gamma, beta, out + D);
}